// Round 20
// baseline (229.961 us; speedup 1.0000x reference)
//
#include <hip/hip_runtime.h>

#define N_NODES 100000
#define N_EDGES 1600000
#define NBUCK 1563        // ceil(100000/64) buckets of 64 dst nodes
#define NBLK 256          // blocks for count/fill passes
#define PER_BLK 6250      // 256*6250 = 1.6M exact
#define MAX_BE 2048       // LDS capacity per bucket (mean 1024, max ~1150)
#define PB_BLKS 196       // ceil(100000/512) prep_B blocks in fused dispatch

// ws layout (bytes):
//  cntg16 @ 0       : [256][1563] u16 (800256)
//  tot    @ 800256  : 1563 u32
//  base   @ 806512  : 1564 u32
//  stats  @ 812800  : 128 f64 (1024)
//  done   @ 813824  : 1 u32 (pad 32)
//  U      @ 813856  : 64x128 f32 (32768)   U[i][k*64+o]
//  pay    @ 846624  : N_EDGES u32   (dst&63)<<18 | src<<1 | ord, bucket-sorted
//  B      @ 7246624 : 2*N_NODES x 64 bf16 (25.6MB), row p = src*2+ord

__device__ __forceinline__ unsigned short f2bf(float x) {
  unsigned u = __float_as_uint(x);
  unsigned r = (u + 0x7FFFu + ((u >> 16) & 1u)) >> 16;
  return (unsigned short)r;
}

// Fused: blocks [0,NBLK) = per-block bucket histogram; blocks [NBLK,NBLK+16)
// = prep_U body (8192 threads) + stats/done zeroing.
__global__ __launch_bounds__(512) void count_prepU(
    const int* __restrict__ edst, unsigned short* __restrict__ cntg16,
    const float* __restrict__ linear, const float* __restrict__ mlp_w,
    float* __restrict__ U, double* __restrict__ stats,
    unsigned* __restrict__ done) {
  __shared__ unsigned h[NBUCK];
  if (blockIdx.x < NBLK) {
    for (int i = threadIdx.x; i < NBUCK; i += 512) h[i] = 0;
    __syncthreads();
    const int k = blockIdx.x;
    const int beg = k * PER_BLK, end = beg + PER_BLK;
    for (int e = beg + (int)threadIdx.x; e < end; e += 512)
      atomicAdd(&h[((unsigned)edst[e]) >> 6], 1u);
    __syncthreads();
    for (int i = threadIdx.x; i < NBUCK; i += 512)
      cntg16[(size_t)k * NBUCK + i] = (unsigned short)h[i];
    return;
  }
  const int blk = blockIdx.x - NBLK;  // 0..15
  if (blk == 0 && threadIdx.x < 128) stats[threadIdx.x] = 0.0;
  if (blk == 0 && threadIdx.x == 128) *done = 0u;
  int idx = blk * 512 + threadIdx.x;  // 8192 outputs
  int o = idx & 63;
  int ki = idx >> 6;
  int k = ki >> 6, i = ki & 63;
  float acc = 0.f;
#pragma unroll 8
  for (int j = 0; j < 64; ++j)
    acc += linear[ki * 64 + j] * mlp_w[o * 64 + j];
  U[i * 128 + k * 64 + o] = acc;
}

// scanT1 (per-bucket scan over 256 block counts) + last-block scanT2.
__global__ __launch_bounds__(256) void scanT1T2(unsigned short* __restrict__ cntg16,
                                                unsigned* __restrict__ tot,
                                                unsigned* __restrict__ base,
                                                unsigned* __restrict__ done) {
  const int lane = threadIdx.x & 63;
  const int wv = threadIdx.x >> 6;
  const int b = blockIdx.x * 4 + wv;
  if (b < NBUCK) {
    unsigned c[4];
    unsigned lsum = 0;
#pragma unroll
    for (int j = 0; j < 4; ++j) {
      c[j] = cntg16[(size_t)(lane * 4 + j) * NBUCK + b];
      lsum += c[j];
    }
    unsigned inc = lsum;
#pragma unroll
    for (int d = 1; d < 64; d <<= 1) {
      unsigned n = __shfl_up(inc, d);
      if (lane >= d) inc += n;
    }
    unsigned run = inc - lsum;  // exclusive over lanes
#pragma unroll
    for (int j = 0; j < 4; ++j) {
      cntg16[(size_t)(lane * 4 + j) * NBUCK + b] = (unsigned short)run;
      run += c[j];
    }
    unsigned total = __shfl(inc, 63);
    if (lane == 0) tot[b] = total;
  }

  __threadfence();
  __shared__ unsigned isLast;
  if (threadIdx.x == 0)
    isLast = (atomicAdd(done, 1u) == (unsigned)(gridDim.x - 1)) ? 1u : 0u;
  __syncthreads();
  if (!isLast) return;
  __threadfence();  // acquire side

  // ---- scanT2 body (single block, 256 threads)
  __shared__ unsigned sh[256];
  const int t = threadIdx.x;
  unsigned local[7];
  unsigned s = 0;
#pragma unroll
  for (int i = 0; i < 7; ++i) {
    int idx = t * 7 + i;
    local[i] = (idx < NBUCK) ? tot[idx] : 0u;
    s += local[i];
  }
  sh[t] = s;
  __syncthreads();
#pragma unroll
  for (int off = 1; off < 256; off <<= 1) {
    unsigned v = (t >= off) ? sh[t - off] : 0u;
    __syncthreads();
    sh[t] += v;
    __syncthreads();
  }
  unsigned run = sh[t] - s;
#pragma unroll
  for (int i = 0; i < 7; ++i) {
    int idx = t * 7 + i;
    if (idx < NBUCK) { base[idx] = run; run += local[i]; }
  }
  if (t == 0) base[NBUCK] = N_EDGES;
}

// Fused: blocks [0,NBLK) = fillB body; blocks [NBLK,NBLK+PB_BLKS) = prep_B
// at 1 row/thread (64 independent accumulators -> full ILP, ~85 VGPR).
__global__ __launch_bounds__(512) void fill_prepB(
    const int* __restrict__ esrc, const int* __restrict__ edst,
    const int* __restrict__ eord, const unsigned short* __restrict__ cntg16,
    const unsigned* __restrict__ base, unsigned* __restrict__ pay,
    const float* __restrict__ feature, const float* __restrict__ U,
    unsigned short* __restrict__ B) {
  __shared__ float shm[64 * 128];  // 32KB; aliased as curL in fillB branch

  if (blockIdx.x < NBLK) {
    unsigned* curL = reinterpret_cast<unsigned*>(shm);
    const int k = blockIdx.x;
    for (int i = threadIdx.x; i < NBUCK; i += 512)
      curL[i] = base[i] + (unsigned)cntg16[(size_t)k * NBUCK + i];
    __syncthreads();
    const int beg = k * PER_BLK, end = beg + PER_BLK;
    for (int e = beg + (int)threadIdx.x; e < end; e += 512) {
      unsigned d = (unsigned)edst[e];
      unsigned pos = atomicAdd(&curL[d >> 6], 1u);
      pay[pos] = ((d & 63u) << 18) | ((unsigned)esrc[e] << 1) | (unsigned)eord[e];
    }
    return;
  }

  // ---- prep_B branch
  float* Us = shm;
  for (int i = threadIdx.x; i < 64 * 128; i += 512) Us[i] = U[i];
  __syncthreads();
  const int row = (int)(blockIdx.x - NBLK) * 512 + (int)threadIdx.x;
  if (row >= N_NODES) return;
  const float4* Fr = reinterpret_cast<const float4*>(feature + (size_t)row * 64);
#pragma unroll 1
  for (int k = 0; k < 2; ++k) {
    float acc[64];
#pragma unroll
    for (int o = 0; o < 64; ++o) acc[o] = 0.f;
#pragma unroll 2
    for (int i4 = 0; i4 < 16; ++i4) {
      float4 a = Fr[i4];
      float av[4] = {a.x, a.y, a.z, a.w};
#pragma unroll
      for (int u = 0; u < 4; ++u) {
        const float* Ur = &Us[(i4 * 4 + u) * 128 + k * 64];
#pragma unroll
        for (int o = 0; o < 64; ++o) acc[o] = fmaf(av[u], Ur[o], acc[o]);
      }
    }
    ushort4* Bp = reinterpret_cast<ushort4*>(B + (((size_t)row * 2 + k) << 6));
#pragma unroll
    for (int o4 = 0; o4 < 16; ++o4) {
      ushort4 pk;
      pk.x = f2bf(acc[o4 * 4 + 0]);
      pk.y = f2bf(acc[o4 * 4 + 1]);
      pk.z = f2bf(acc[o4 * 4 + 2]);
      pk.w = f2bf(acc[o4 * 4 + 3]);
      Bp[o4] = pk;
    }
  }
}

// One block per bucket: stage pay run in LDS (read global once), LDS
// counting-sort by dst-low-6, then 16-lane node groups gather uint2
// (4 bf16 ch) per lane per edge (R13-verified body).
__global__ __launch_bounds__(256) void bgather(const unsigned* __restrict__ base,
                                               const unsigned* __restrict__ pay,
                                               const unsigned short* __restrict__ B,
                                               const float* __restrict__ bias,
                                               float* __restrict__ out,
                                               double* __restrict__ stats) {
  __shared__ unsigned hist[64];
  __shared__ unsigned offsL[65];
  __shared__ unsigned curN[64];
  __shared__ unsigned pay_raw[MAX_BE];
  __shared__ unsigned pay_s[MAX_BE];
  __shared__ double dd0[4][64];
  __shared__ double dd1[4][64];
  const int tid = threadIdx.x;
  const int lane = tid & 63;
  const int wv = tid >> 6;
  const int b = blockIdx.x;
  const unsigned base0 = base[b];
  const unsigned n_e = base[b + 1] - base0;

  if (tid < 64) hist[tid] = 0;
  __syncthreads();
  for (unsigned i = tid; i < n_e; i += 256) {
    unsigned w = pay[base0 + i];
    pay_raw[i] = w;
    atomicAdd(&hist[w >> 18], 1u);
  }
  __syncthreads();
  if (wv == 0) {
    unsigned hv = hist[lane];
    unsigned inc = hv;
#pragma unroll
    for (int d = 1; d < 64; d <<= 1) {
      unsigned n = __shfl_up(inc, d);
      if (lane >= d) inc += n;
    }
    offsL[lane + 1] = inc;
    if (lane == 0) offsL[0] = 0;
    curN[lane] = inc - hv;
  }
  __syncthreads();
  for (unsigned i = tid; i < n_e; i += 256) {
    unsigned w = pay_raw[i];
    unsigned pos = atomicAdd(&curN[w >> 18], 1u);
    pay_s[pos] = w;
  }
  __syncthreads();

  const int g = tid >> 4;        // group 0..15, owns nodes g*4..g*4+3
  const int sl = tid & 15;       // sub-lane
  const int c0 = sl << 2;        // first channel
  const float4 bo4 = *reinterpret_cast<const float4*>(bias + c0);
  double s0[4] = {0, 0, 0, 0}, s1[4] = {0, 0, 0, 0};

#pragma unroll
  for (int i = 0; i < 4; ++i) {
    const int nl = (g << 2) + i;
    const int ng = (b << 6) + nl;
    unsigned e = offsL[nl];
    const unsigned e1 = offsL[nl + 1];
    float s[4] = {0.f, 0.f, 0.f, 0.f};
    while (e < e1) {
      unsigned rem = e1 - e;
      int cnt = rem < 8u ? (int)rem : 8;
      unsigned p[8];
      uint2 v[8];
#pragma unroll
      for (int j = 0; j < 8; ++j)
        p[j] = pay_s[e + (j < cnt ? (unsigned)j : 0u)];
#pragma unroll
      for (int j = 0; j < 8; ++j)
        v[j] = *reinterpret_cast<const uint2*>(
            B + (((size_t)(p[j] & 0x3FFFFu)) << 6) + c0);
#pragma unroll
      for (int j = 0; j < 8; ++j) {
        if (j < cnt) {
          s[0] += __uint_as_float(v[j].x << 16);
          s[1] += __uint_as_float(v[j].x & 0xFFFF0000u);
          s[2] += __uint_as_float(v[j].y << 16);
          s[3] += __uint_as_float(v[j].y & 0xFFFF0000u);
        }
      }
      e += cnt;
    }
    if (ng < N_NODES) {
      float4 r;
      r.x = fmaxf(s[0] + bo4.x, 0.f);
      r.y = fmaxf(s[1] + bo4.y, 0.f);
      r.z = fmaxf(s[2] + bo4.z, 0.f);
      r.w = fmaxf(s[3] + bo4.w, 0.f);
      *reinterpret_cast<float4*>(out + ((size_t)ng << 6) + c0) = r;
      s0[0] += (double)r.x; s1[0] += (double)r.x * (double)r.x;
      s0[1] += (double)r.y; s1[1] += (double)r.y * (double)r.y;
      s0[2] += (double)r.z; s1[2] += (double)r.z * (double)r.z;
      s0[3] += (double)r.w; s1[3] += (double)r.w * (double)r.w;
    }
  }

  // stats reduce: lanes {sl, sl+16, sl+32, sl+48} own the same channels
#pragma unroll
  for (int q = 0; q < 4; ++q) {
    double v0 = s0[q], v1 = s1[q];
    v0 += __shfl_xor(v0, 16); v0 += __shfl_xor(v0, 32);
    v1 += __shfl_xor(v1, 16); v1 += __shfl_xor(v1, 32);
    s0[q] = v0; s1[q] = v1;
  }
  if ((lane & 48) == 0) {
#pragma unroll
    for (int q = 0; q < 4; ++q) {
      dd0[wv][c0 + q] = s0[q];
      dd1[wv][c0 + q] = s1[q];
    }
  }
  __syncthreads();
  if (tid < 64) {
    double t0 = dd0[0][tid] + dd0[1][tid] + dd0[2][tid] + dd0[3][tid];
    double t1 = dd1[0][tid] + dd1[1][tid] + dd1[2][tid] + dd1[3][tid];
    atomicAdd(&stats[tid], t0);
    atomicAdd(&stats[64 + tid], t1);
  }
}

// float4-vectorized; stride (blocks*256) divisible by 16 keeps each thread's
// channel group constant across the grid-stride loop.
__global__ __launch_bounds__(256) void bn_apply(float* __restrict__ h,
                                                const double* __restrict__ stats,
                                                const float* __restrict__ gamma,
                                                const float* __restrict__ beta) {
  const int idx0 = blockIdx.x * 256 + threadIdx.x;
  const int cg = (idx0 & 15) << 2;
  float sc[4], sh[4];
#pragma unroll
  for (int q = 0; q < 4; ++q) {
    double mean = stats[cg + q] * (1.0 / N_NODES);
    double var = stats[64 + cg + q] * (1.0 / N_NODES) - mean * mean;
    float inv = (float)(1.0 / sqrt(var + 1e-5));
    sc[q] = gamma[cg + q] * inv;
    sh[q] = beta[cg + q] - (float)mean * sc[q];
  }
  float4* h4 = reinterpret_cast<float4*>(h);
  const int total = N_NODES * 16;
  const int stride = gridDim.x * 256;
  for (int idx = idx0; idx < total; idx += stride) {
    float4 v = h4[idx];
    v.x = v.x * sc[0] + sh[0];
    v.y = v.y * sc[1] + sh[1];
    v.z = v.z * sc[2] + sh[2];
    v.w = v.w * sc[3] + sh[3];
    h4[idx] = v;
  }
}

extern "C" void kernel_launch(void* const* d_in, const int* in_sizes, int n_in,
                              void* d_out, int out_size, void* d_ws, size_t ws_size,
                              hipStream_t stream) {
  const float* feature = (const float*)d_in[0];
  // d_in[1] = sp_embeddings (unused)
  const float* linear = (const float*)d_in[2];
  const float* mlp_w  = (const float*)d_in[3];
  const float* mlp_b  = (const float*)d_in[4];
  const float* gamma  = (const float*)d_in[5];
  const float* beta   = (const float*)d_in[6];
  const int* esrc = (const int*)d_in[7];
  const int* edst = (const int*)d_in[8];
  const int* eord = (const int*)d_in[9];
  float* out = (float*)d_out;

  char* basep = (char*)d_ws;
  unsigned short* cntg16 = (unsigned short*)(basep);
  unsigned*       tot    = (unsigned*)(basep + 800256);
  unsigned*       base   = (unsigned*)(basep + 806512);
  double*         stats  = (double*)  (basep + 812800);
  unsigned*       done   = (unsigned*)(basep + 813824);
  float*          U      = (float*)   (basep + 813856);
  unsigned*       pay    = (unsigned*)(basep + 846624);
  unsigned short* B      = (unsigned short*)(basep + 7246624);

  count_prepU<<<NBLK + 16, 512, 0, stream>>>(edst, cntg16, linear, mlp_w, U,
                                             stats, done);
  scanT1T2<<<(NBUCK + 3) / 4, 256, 0, stream>>>(cntg16, tot, base, done);
  fill_prepB<<<NBLK + PB_BLKS, 512, 0, stream>>>(esrc, edst, eord, cntg16,
                                                 base, pay, feature, U, B);
  bgather<<<NBUCK, 256, 0, stream>>>(base, pay, B, mlp_b, out, stats);
  bn_apply<<<1024, 256, 0, stream>>>(out, stats, gamma, beta);
}

// Round 21
// 155.458 us; speedup vs baseline: 1.4792x; 1.4792x over previous
//
#include <hip/hip_runtime.h>

#define N_NODES 100000
#define N_EDGES 1600000
#define NBUCK 1563        // ceil(100000/64) buckets of 64 dst nodes
#define NBLK 256          // blocks for count/fill passes
#define PER_BLK 6250      // 256*6250 = 1.6M exact
#define MAX_BE 2048       // LDS capacity per bucket (mean 1024, max ~1150)

// ws layout (bytes):
//  cntg16 @ 0       : [256][1563] u16 (800256)  per-(block,bucket) counts -> offsets
//  tot    @ 800256  : 1563 u32
//  base   @ 806512  : 1564 u32
//  stats  @ 812800  : 128 f64
//  U      @ 813824  : 64x128 f32 (32768)   U[i][k*64+o]
//  pay    @ 846592  : N_EDGES u32   (dst&63)<<18 | src<<1 | ord, bucket-sorted
//  B      @ 7246592 : 2*N_NODES x 64 bf16 (25.6MB), row p = src*2+ord

__device__ __forceinline__ unsigned short f2bf(float x) {
  unsigned u = __float_as_uint(x);
  unsigned r = (u + 0x7FFFu + ((u >> 16) & 1u)) >> 16;
  return (unsigned short)r;
}

// Fused: blocks [0,NBLK) = per-block bucket histogram (countA body);
//        blocks [NBLK,NBLK+16) = prep_U body (8192 threads) + stats zeroing.
__global__ __launch_bounds__(512) void count_prepU(
    const int* __restrict__ edst, unsigned short* __restrict__ cntg16,
    const float* __restrict__ linear, const float* __restrict__ mlp_w,
    float* __restrict__ U, double* __restrict__ stats) {
  __shared__ unsigned h[NBUCK];
  if (blockIdx.x < NBLK) {
    for (int i = threadIdx.x; i < NBUCK; i += 512) h[i] = 0;
    __syncthreads();
    const int k = blockIdx.x;
    const int beg = k * PER_BLK, end = beg + PER_BLK;
    for (int e = beg + (int)threadIdx.x; e < end; e += 512)
      atomicAdd(&h[((unsigned)edst[e]) >> 6], 1u);
    __syncthreads();
    for (int i = threadIdx.x; i < NBUCK; i += 512)
      cntg16[(size_t)k * NBUCK + i] = (unsigned short)h[i];
    return;
  }
  const int blk = blockIdx.x - NBLK;  // 0..15
  if (blk == 0 && threadIdx.x < 128) stats[threadIdx.x] = 0.0;
  int idx = blk * 512 + threadIdx.x;  // 8192 outputs
  int o = idx & 63;
  int ki = idx >> 6;
  int k = ki >> 6, i = ki & 63;
  float acc = 0.f;
#pragma unroll 8
  for (int j = 0; j < 64; ++j)
    acc += linear[ki * 64 + j] * mlp_w[o * 64 + j];
  U[i * 128 + k * 64 + o] = acc;
}

// 2 rows per thread: LDS Us reads amortized over both rows; 128 independent
// accumulators give the ILP that hides FMA latency (R13-verified).
// 256-thread block REQUIRED: acc0[64]+acc1[64] needs the 256-VGPR budget
// (512-thread blocks cap at 128 VGPR -> scratch spill; R16/R20 both failed).
__global__ __launch_bounds__(256) void prep_B(const float* __restrict__ feature,
                                              const float* __restrict__ U,
                                              unsigned short* __restrict__ B) {
  __shared__ float Us[64 * 128];
  for (int i = threadIdx.x; i < 64 * 128; i += 256) Us[i] = U[i];
  __syncthreads();
  const int ra = blockIdx.x * 512 + threadIdx.x;
  const int rb = ra + 256;
  const bool va = ra < N_NODES, vb = rb < N_NODES;
  const float4* Fa = reinterpret_cast<const float4*>(feature + (size_t)(va ? ra : 0) * 64);
  const float4* Fb = reinterpret_cast<const float4*>(feature + (size_t)(vb ? rb : 0) * 64);
#pragma unroll
  for (int k = 0; k < 2; ++k) {
    float acc0[64], acc1[64];
#pragma unroll
    for (int o = 0; o < 64; ++o) { acc0[o] = 0.f; acc1[o] = 0.f; }
#pragma unroll 2
    for (int i4 = 0; i4 < 16; ++i4) {
      float4 a = Fa[i4];
      float4 cc = Fb[i4];
      float av[4] = {a.x, a.y, a.z, a.w};
      float cv[4] = {cc.x, cc.y, cc.z, cc.w};
#pragma unroll
      for (int u = 0; u < 4; ++u) {
        const float* Ur = &Us[(i4 * 4 + u) * 128 + k * 64];
#pragma unroll
        for (int o = 0; o < 64; ++o) {
          float w = Ur[o];
          acc0[o] = fmaf(av[u], w, acc0[o]);
          acc1[o] = fmaf(cv[u], w, acc1[o]);
        }
      }
    }
    if (va) {
      ushort4* Bp = reinterpret_cast<ushort4*>(B + (((size_t)ra * 2 + k) << 6));
#pragma unroll
      for (int o4 = 0; o4 < 16; ++o4) {
        ushort4 pk;
        pk.x = f2bf(acc0[o4 * 4 + 0]);
        pk.y = f2bf(acc0[o4 * 4 + 1]);
        pk.z = f2bf(acc0[o4 * 4 + 2]);
        pk.w = f2bf(acc0[o4 * 4 + 3]);
        Bp[o4] = pk;
      }
    }
    if (vb) {
      ushort4* Bp = reinterpret_cast<ushort4*>(B + (((size_t)rb * 2 + k) << 6));
#pragma unroll
      for (int o4 = 0; o4 < 16; ++o4) {
        ushort4 pk;
        pk.x = f2bf(acc1[o4 * 4 + 0]);
        pk.y = f2bf(acc1[o4 * 4 + 1]);
        pk.z = f2bf(acc1[o4 * 4 + 2]);
        pk.w = f2bf(acc1[o4 * 4 + 3]);
        Bp[o4] = pk;
      }
    }
  }
}

// Per bucket b: exclusive scan over the 256 block counts (lane covers 4).
__global__ __launch_bounds__(256) void scanT1(unsigned short* __restrict__ cntg16,
                                              unsigned* __restrict__ tot) {
  const int lane = threadIdx.x & 63;
  const int wv = threadIdx.x >> 6;
  const int b = blockIdx.x * 4 + wv;
  if (b >= NBUCK) return;
  unsigned c[4];
  unsigned lsum = 0;
#pragma unroll
  for (int j = 0; j < 4; ++j) {
    c[j] = cntg16[(size_t)(lane * 4 + j) * NBUCK + b];
    lsum += c[j];
  }
  unsigned inc = lsum;
#pragma unroll
  for (int d = 1; d < 64; d <<= 1) {
    unsigned n = __shfl_up(inc, d);
    if (lane >= d) inc += n;
  }
  unsigned run = inc - lsum;  // exclusive over lanes
#pragma unroll
  for (int j = 0; j < 4; ++j) {
    cntg16[(size_t)(lane * 4 + j) * NBUCK + b] = (unsigned short)run;
    run += c[j];
  }
  unsigned total = __shfl(inc, 63);
  if (lane == 0) tot[b] = total;
}

__global__ __launch_bounds__(256) void scanT2(const unsigned* __restrict__ tot,
                                              unsigned* __restrict__ base) {
  __shared__ unsigned sh[256];
  const int t = threadIdx.x;
  unsigned local[7];
  unsigned s = 0;
#pragma unroll
  for (int i = 0; i < 7; ++i) {
    int idx = t * 7 + i;
    local[i] = (idx < NBUCK) ? tot[idx] : 0u;
    s += local[i];
  }
  sh[t] = s;
  __syncthreads();
#pragma unroll
  for (int off = 1; off < 256; off <<= 1) {
    unsigned v = (t >= off) ? sh[t - off] : 0u;
    __syncthreads();
    sh[t] += v;
    __syncthreads();
  }
  unsigned run = sh[t] - s;
#pragma unroll
  for (int i = 0; i < 7; ++i) {
    int idx = t * 7 + i;
    if (idx < NBUCK) { base[idx] = run; run += local[i]; }
  }
  if (t == 0) base[NBUCK] = N_EDGES;
}

__global__ __launch_bounds__(512) void fillB(const int* __restrict__ esrc,
                                             const int* __restrict__ edst,
                                             const int* __restrict__ eord,
                                             const unsigned short* __restrict__ cntg16,
                                             const unsigned* __restrict__ base,
                                             unsigned* __restrict__ pay) {
  __shared__ unsigned curL[NBUCK];
  const int k = blockIdx.x;
  for (int i = threadIdx.x; i < NBUCK; i += 512)
    curL[i] = base[i] + (unsigned)cntg16[(size_t)k * NBUCK + i];
  __syncthreads();
  const int beg = k * PER_BLK, end = beg + PER_BLK;
  for (int e = beg + (int)threadIdx.x; e < end; e += 512) {
    unsigned d = (unsigned)edst[e];
    unsigned pos = atomicAdd(&curL[d >> 6], 1u);
    pay[pos] = ((d & 63u) << 18) | ((unsigned)esrc[e] << 1) | (unsigned)eord[e];
  }
}

// One block per bucket: stage pay run in LDS (read global once), LDS
// counting-sort by dst-low-6, then 16-lane node groups gather uint2
// (4 bf16 ch) per lane per edge (R13-verified body).
__global__ __launch_bounds__(256) void bgather(const unsigned* __restrict__ base,
                                               const unsigned* __restrict__ pay,
                                               const unsigned short* __restrict__ B,
                                               const float* __restrict__ bias,
                                               float* __restrict__ out,
                                               double* __restrict__ stats) {
  __shared__ unsigned hist[64];
  __shared__ unsigned offsL[65];
  __shared__ unsigned curN[64];
  __shared__ unsigned pay_raw[MAX_BE];
  __shared__ unsigned pay_s[MAX_BE];
  __shared__ double dd0[4][64];
  __shared__ double dd1[4][64];
  const int tid = threadIdx.x;
  const int lane = tid & 63;
  const int wv = tid >> 6;
  const int b = blockIdx.x;
  const unsigned base0 = base[b];
  const unsigned n_e = base[b + 1] - base0;

  if (tid < 64) hist[tid] = 0;
  __syncthreads();
  for (unsigned i = tid; i < n_e; i += 256) {
    unsigned w = pay[base0 + i];
    pay_raw[i] = w;
    atomicAdd(&hist[w >> 18], 1u);
  }
  __syncthreads();
  if (wv == 0) {
    unsigned hv = hist[lane];
    unsigned inc = hv;
#pragma unroll
    for (int d = 1; d < 64; d <<= 1) {
      unsigned n = __shfl_up(inc, d);
      if (lane >= d) inc += n;
    }
    offsL[lane + 1] = inc;
    if (lane == 0) offsL[0] = 0;
    curN[lane] = inc - hv;
  }
  __syncthreads();
  for (unsigned i = tid; i < n_e; i += 256) {
    unsigned w = pay_raw[i];
    unsigned pos = atomicAdd(&curN[w >> 18], 1u);
    pay_s[pos] = w;
  }
  __syncthreads();

  const int g = tid >> 4;        // group 0..15, owns nodes g*4..g*4+3
  const int sl = tid & 15;       // sub-lane
  const int c0 = sl << 2;        // first channel
  const float4 bo4 = *reinterpret_cast<const float4*>(bias + c0);
  double s0[4] = {0, 0, 0, 0}, s1[4] = {0, 0, 0, 0};

#pragma unroll
  for (int i = 0; i < 4; ++i) {
    const int nl = (g << 2) + i;
    const int ng = (b << 6) + nl;
    unsigned e = offsL[nl];
    const unsigned e1 = offsL[nl + 1];
    float s[4] = {0.f, 0.f, 0.f, 0.f};
    while (e < e1) {
      unsigned rem = e1 - e;
      int cnt = rem < 8u ? (int)rem : 8;
      unsigned p[8];
      uint2 v[8];
#pragma unroll
      for (int j = 0; j < 8; ++j)
        p[j] = pay_s[e + (j < cnt ? (unsigned)j : 0u)];
#pragma unroll
      for (int j = 0; j < 8; ++j)
        v[j] = *reinterpret_cast<const uint2*>(
            B + (((size_t)(p[j] & 0x3FFFFu)) << 6) + c0);
#pragma unroll
      for (int j = 0; j < 8; ++j) {
        if (j < cnt) {
          s[0] += __uint_as_float(v[j].x << 16);
          s[1] += __uint_as_float(v[j].x & 0xFFFF0000u);
          s[2] += __uint_as_float(v[j].y << 16);
          s[3] += __uint_as_float(v[j].y & 0xFFFF0000u);
        }
      }
      e += cnt;
    }
    if (ng < N_NODES) {
      float4 r;
      r.x = fmaxf(s[0] + bo4.x, 0.f);
      r.y = fmaxf(s[1] + bo4.y, 0.f);
      r.z = fmaxf(s[2] + bo4.z, 0.f);
      r.w = fmaxf(s[3] + bo4.w, 0.f);
      *reinterpret_cast<float4*>(out + ((size_t)ng << 6) + c0) = r;
      s0[0] += (double)r.x; s1[0] += (double)r.x * (double)r.x;
      s0[1] += (double)r.y; s1[1] += (double)r.y * (double)r.y;
      s0[2] += (double)r.z; s1[2] += (double)r.z * (double)r.z;
      s0[3] += (double)r.w; s1[3] += (double)r.w * (double)r.w;
    }
  }

  // stats reduce: lanes {sl, sl+16, sl+32, sl+48} own the same channels
#pragma unroll
  for (int q = 0; q < 4; ++q) {
    double v0 = s0[q], v1 = s1[q];
    v0 += __shfl_xor(v0, 16); v0 += __shfl_xor(v0, 32);
    v1 += __shfl_xor(v1, 16); v1 += __shfl_xor(v1, 32);
    s0[q] = v0; s1[q] = v1;
  }
  if ((lane & 48) == 0) {
#pragma unroll
    for (int q = 0; q < 4; ++q) {
      dd0[wv][c0 + q] = s0[q];
      dd1[wv][c0 + q] = s1[q];
    }
  }
  __syncthreads();
  if (tid < 64) {
    double t0 = dd0[0][tid] + dd0[1][tid] + dd0[2][tid] + dd0[3][tid];
    double t1 = dd1[0][tid] + dd1[1][tid] + dd1[2][tid] + dd1[3][tid];
    atomicAdd(&stats[tid], t0);
    atomicAdd(&stats[64 + tid], t1);
  }
}

// float4-vectorized; stride (blocks*256) divisible by 16 keeps each thread's
// channel group constant across the grid-stride loop.
__global__ __launch_bounds__(256) void bn_apply(float* __restrict__ h,
                                                const double* __restrict__ stats,
                                                const float* __restrict__ gamma,
                                                const float* __restrict__ beta) {
  const int idx0 = blockIdx.x * 256 + threadIdx.x;
  const int cg = (idx0 & 15) << 2;
  float sc[4], sh[4];
#pragma unroll
  for (int q = 0; q < 4; ++q) {
    double mean = stats[cg + q] * (1.0 / N_NODES);
    double var = stats[64 + cg + q] * (1.0 / N_NODES) - mean * mean;
    float inv = (float)(1.0 / sqrt(var + 1e-5));
    sc[q] = gamma[cg + q] * inv;
    sh[q] = beta[cg + q] - (float)mean * sc[q];
  }
  float4* h4 = reinterpret_cast<float4*>(h);
  const int total = N_NODES * 16;
  const int stride = gridDim.x * 256;
  for (int idx = idx0; idx < total; idx += stride) {
    float4 v = h4[idx];
    v.x = v.x * sc[0] + sh[0];
    v.y = v.y * sc[1] + sh[1];
    v.z = v.z * sc[2] + sh[2];
    v.w = v.w * sc[3] + sh[3];
    h4[idx] = v;
  }
}

extern "C" void kernel_launch(void* const* d_in, const int* in_sizes, int n_in,
                              void* d_out, int out_size, void* d_ws, size_t ws_size,
                              hipStream_t stream) {
  const float* feature = (const float*)d_in[0];
  // d_in[1] = sp_embeddings (unused)
  const float* linear = (const float*)d_in[2];
  const float* mlp_w  = (const float*)d_in[3];
  const float* mlp_b  = (const float*)d_in[4];
  const float* gamma  = (const float*)d_in[5];
  const float* beta   = (const float*)d_in[6];
  const int* esrc = (const int*)d_in[7];
  const int* edst = (const int*)d_in[8];
  const int* eord = (const int*)d_in[9];
  float* out = (float*)d_out;

  char* basep = (char*)d_ws;
  unsigned short* cntg16 = (unsigned short*)(basep);
  unsigned*       tot    = (unsigned*)(basep + 800256);
  unsigned*       base   = (unsigned*)(basep + 806512);
  double*         stats  = (double*)  (basep + 812800);
  float*          U      = (float*)   (basep + 813824);
  unsigned*       pay    = (unsigned*)(basep + 846592);
  unsigned short* B      = (unsigned short*)(basep + 7246592);

  count_prepU<<<NBLK + 16, 512, 0, stream>>>(edst, cntg16, linear, mlp_w, U, stats);
  scanT1<<<(NBUCK + 3) / 4, 256, 0, stream>>>(cntg16, tot);
  scanT2<<<1, 256, 0, stream>>>(tot, base);
  fillB<<<NBLK, 512, 0, stream>>>(esrc, edst, eord, cntg16, base, pay);
  prep_B<<<(N_NODES + 511) / 512, 256, 0, stream>>>(feature, U, B);
  bgather<<<NBUCK, 256, 0, stream>>>(base, pay, B, mlp_b, out, stats);
  bn_apply<<<1024, 256, 0, stream>>>(out, stats, gamma, beta);
}